// Round 13
// baseline (414.471 us; speedup 1.0000x reference)
//
#include <hip/hip_runtime.h>
#include <math.h>

#define NH 16
#define TT 1024
#define HD 64
#define NE 1024
#define NBLK 768

typedef unsigned int u32;
typedef unsigned short u16;
typedef __bf16 bf16x8 __attribute__((ext_vector_type(8)));
typedef float f32x4 __attribute__((ext_vector_type(4)));

__device__ inline u16 f2bf(float f) {
  u32 u = __builtin_bit_cast(u32, f);
  u32 r = (u + 0x7fffu + ((u >> 16) & 1u)) >> 16;
  return (u16)r;
}
__device__ inline float bf2f(u16 h) {
  return __builtin_bit_cast(float, (u32)h << 16);
}
__device__ inline void gload16(const void* g, void* l) {
  __builtin_amdgcn_global_load_lds((const __attribute__((address_space(1))) void*)g,
                                   (__attribute__((address_space(3))) void*)l, 16, 0, 0);
}
__device__ inline u16 h16(uint4 v, int e) {
  u32 w = ((const u32*)&v)[e >> 1];
  return (e & 1) ? (u16)(w >> 16) : (u16)(w & 0xffffu);
}
__device__ inline void block_bar() {
  asm volatile("" ::: "memory");
  __builtin_amdgcn_s_barrier();
  asm volatile("" ::: "memory");
}

// Software grid barrier: agent-scope atomics + fences (cross-XCD safe).
// Counter must be zeroed before each launch (host memsetAsync).
__device__ __forceinline__ void grid_barrier(u32* cnt) {
  __syncthreads();
  if (threadIdx.x == 0) {
    __threadfence();   // release: L2 writeback (agent scope)
    __hip_atomic_fetch_add(cnt, 1u, __ATOMIC_RELEASE, __HIP_MEMORY_SCOPE_AGENT);
    while (__hip_atomic_load(cnt, __ATOMIC_ACQUIRE, __HIP_MEMORY_SCOPE_AGENT) < (u32)NBLK) {
      __builtin_amdgcn_s_sleep(8);
    }
    __threadfence();   // acquire: invalidate stale caches
  }
  __syncthreads();
}

// ---- Phase bodies (bit-identical math to the R9/R12 kernels) ----

// prep unit u: u<1024 -> x f32->bf16 chunk; else 64x64 weight transpose tile.
__device__ __forceinline__ void prep_unit(int u, int tid,
    const float* __restrict__ x, const float* __restrict__ Wqkv,
    const float* __restrict__ Wout, u16* __restrict__ xb,
    u16* __restrict__ WqkvT, u16* __restrict__ WoutT, char* SM) {
  if (u < 1024) {
    int i = u * 256 + tid;
    float4 f = ((const float4*)x)[i];
    ushort4 o = {f2bf(f.x), f2bf(f.y), f2bf(f.z), f2bf(f.w)};
    ((ushort4*)xb)[i] = o;
    return;
  }
  float (*tile)[65] = (float(*)[65])SM;
  int b = u - 1024;
  int nb = b & 63, kb = b >> 6;
  const float* W; u16* WT; int N, n0;
  if (nb < 48) { W = Wqkv; WT = WqkvT; N = 3 * NE; n0 = nb * 64; }
  else         { W = Wout; WT = WoutT; N = NE;     n0 = (nb - 48) * 64; }
  const int k0 = kb * 64;
#pragma unroll
  for (int it = 0; it < 16; ++it) {
    int idx = it * 256 + tid;
    int r = idx >> 6, c = idx & 63;
    tile[r][c] = W[(size_t)(k0 + r) * N + n0 + c];
  }
  __syncthreads();
#pragma unroll
  for (int it = 0; it < 16; ++it) {
    int idx = it * 256 + tid;
    int nn = idx >> 6, kk = idx & 63;
    WT[(size_t)(n0 + nn) * NE + k0 + kk] = f2bf(tile[kk][nn]);
  }
}

// Stage R rows x 64 k of bf16 into LDS, chunk-swizzled: slot(r,kg)=kg^(r&7).
template<int R>
__device__ __forceinline__ void stage_rows(const u16* __restrict__ G, int ldk,
                                           u16* L, int tid) {
#pragma unroll
  for (int it = 0; it < R / 32; ++it) {
    int idx = it * 256 + tid;
    int r = idx >> 3, kg = idx & 7;
    gload16(G + (size_t)r * ldk + ((kg ^ (r & 7)) << 3), L + (idx << 3));
  }
}

// bf16 MFMA GEMM phase: 64 x NT tile, BK=64, 2-deep counted-vmcnt prefetch.
// MODE 0: f32 direct write. MODE 1: bf16 qkv scatter [which][h][t][d].
template<int MODE, int NT, int CPX>
__device__ __forceinline__ void gemm_phase(const u16* __restrict__ A,
                                           const u16* __restrict__ Bt,
                                           void* __restrict__ Cv,
                                           int N, int K, char* SM, int bid, int tid) {
  u16* AsB = (u16*)SM;                 // 2 x 4096 u16
  u16* BsB = (u16*)(SM + 16384);       // 2 x NT*64 u16
  constexpr int BSTR = NT * 64;
  const int lane = tid & 63;
  const int wv = tid >> 6;
  const int wm = wv >> 1, wn = wv & 1;
  const int xcd = bid & 7, loc = bid >> 3;
  const int row0 = (loc / CPX) * 64;
  const int col0 = (xcd * CPX + loc % CPX) * NT;
  const int nsteps = K >> 6;
  constexpr int NI = NT / 32;
  constexpr int SPW = 2 + NI;

  const u16* Ab = A + (size_t)row0 * K;
  const u16* Bb = Bt + (size_t)col0 * K;

  f32x4 acc[2][NI] = {};

  stage_rows<64>(Ab, K, AsB, tid);
  stage_rows<NT>(Bb, K, BsB, tid);
  stage_rows<64>(Ab + 64, K, AsB + 4096, tid);
  stage_rows<NT>(Bb + 64, K, BsB + BSTR, tid);

  for (int ks = 0; ks < nsteps; ++ks) {
    if (ks < nsteps - 1) {
      if constexpr (SPW == 4) asm volatile("s_waitcnt vmcnt(4)" ::: "memory");
      else                    asm volatile("s_waitcnt vmcnt(3)" ::: "memory");
    } else {
      asm volatile("s_waitcnt vmcnt(0)" ::: "memory");
    }
    __builtin_amdgcn_sched_barrier(0);
    block_bar();

    const int buf = ks & 1;
    const u16* Asb = AsB + buf * 4096;
    const u16* Bsb = BsB + buf * BSTR;
#pragma unroll
    for (int half = 0; half < 2; ++half) {
      const int kk = half * 32;
      bf16x8 af[2], bfr[NI];
#pragma unroll
      for (int mi = 0; mi < 2; ++mi) {
        int r = wm * 32 + mi * 16 + (lane & 15);
        int c = (kk >> 3) + (lane >> 4);
        af[mi] = *(const bf16x8*)&Asb[(r * 8 + (c ^ (r & 7))) * 8];
      }
#pragma unroll
      for (int ni = 0; ni < NI; ++ni) {
        int r = wn * (NT / 2) + ni * 16 + (lane & 15);
        int c = (kk >> 3) + (lane >> 4);
        bfr[ni] = *(const bf16x8*)&Bsb[(r * 8 + (c ^ (r & 7))) * 8];
      }
#pragma unroll
      for (int mi = 0; mi < 2; ++mi)
#pragma unroll
        for (int ni = 0; ni < NI; ++ni)
          acc[mi][ni] = __builtin_amdgcn_mfma_f32_16x16x32_bf16(af[mi], bfr[ni], acc[mi][ni], 0, 0, 0);
    }

    block_bar();
    if (ks + 2 < nsteps) {
      stage_rows<64>(Ab + (size_t)(ks + 2) * 64, K, AsB + buf * 4096, tid);
      stage_rows<NT>(Bb + (size_t)(ks + 2) * 64, K, BsB + buf * BSTR, tid);
    }
  }

  const int rbase = row0 + wm * 32 + (lane >> 4) * 4;
  const int cbase = col0 + wn * (NT / 2) + (lane & 15);
#pragma unroll
  for (int mi = 0; mi < 2; ++mi) {
#pragma unroll
    for (int ni = 0; ni < NI; ++ni) {
      int n = cbase + ni * 16;
#pragma unroll
      for (int r = 0; r < 4; ++r) {
        int t = rbase + mi * 16 + r;
        float val = acc[mi][ni][r];
        if (MODE == 0) {
          ((float*)Cv)[(size_t)t * N + n] = val;
        } else {
          int which = n >> 10, h = (n & 1023) >> 6, d = n & 63;
          ((u16*)Cv)[(size_t)which * (NH * TT * HD) + (size_t)h * (TT * HD) +
                     (size_t)t * HD + d] = f2bf(val);
        }
      }
    }
  }
}

// Tiled gathered attention phase (R9 attn5 body), unit u in [0,1024).
__device__ __forceinline__ void attn_phase(const u16* __restrict__ qkv,
                                           const int* __restrict__ nidx,
                                           u16* __restrict__ y, int D,
                                           char* SM, int u, int tid) {
  u16* Qs = (u16*)SM;                  // 2048 B
  u16* Ks = (u16*)(SM + 2048);         // 16384 B; S/P overlay
  u16* Vt = (u16*)(SM + 18432);        // 16384 B
  int* pn_l = (int*)(SM + 34816);      // 128 B
  int* colj = (int*)(SM + 34944);      // 512 B
  float* rinv = (float*)(SM + 35456);  // 64 B
  float* S = (float*)Ks;
  u16* P = (u16*)((char*)Ks + 8448);

  const int lane = tid & 63;
  const int wv = tid >> 6;
  const int xcd = u & 7, loc = u >> 3;
  const int h = xcd * 2 + (loc & 1);
  const int t0 = (loc >> 1) * 16;

  const u16* qh = qkv + (size_t)h * TT * HD;
  const u16* kh = qkv + (size_t)NH * TT * HD + (size_t)h * TT * HD;
  const u16* vh = qkv + 2 * (size_t)NH * TT * HD + (size_t)h * TT * HD;

  if (tid < 32) pn_l[tid] = nidx[((size_t)h * TT + t0 + (tid >> 1)) * D + (tid & 1)];
  if (tid < 128) {
    int row = tid >> 3, slot = tid & 7, ch = slot ^ (row & 7);
    gload16(qh + (size_t)(t0 + row) * HD + ch * 8, Qs + tid * 8);
  }
  __syncthreads();

  if (tid < 128) {
    int c = tid, j;
    if (c < 80) {
      j = t0 - 64 + c;
      if (j < 0) j = -1;
    } else if (c < 96) {
      j = (c - 80) * 64;
      if (j >= t0 - 64) j = -1;
    } else {
      int s = c - 96;
      j = pn_l[s];
      bool keep = (j < t0 - 64) && ((j & 63) != 0);
      if (keep)
        for (int s2 = 0; s2 < s; ++s2)
          if (pn_l[s2] == j) { keep = false; break; }
      if (!keep) j = -1;
    }
    colj[c] = j;
  }
  __syncthreads();

#pragma unroll
  for (int it = 0; it < 4; ++it) {
    int idx = it * 256 + tid;
    int col = idx >> 3, slot = idx & 7, ch = slot ^ (col & 7);
    int j = colj[col]; if (j < 0) j = 0;
    gload16(kh + (size_t)j * HD + ch * 8, Ks + idx * 8);
  }
  const int d0 = (tid & 7) * 8;
  const int cq = tid >> 3;
  uint4 vreg[4];
#pragma unroll
  for (int it = 0; it < 4; ++it) {
    int col = cq * 4 + it;
    int j = colj[col]; if (j < 0) j = 0;
    vreg[it] = *(const uint4*)(vh + (size_t)j * HD + d0);
  }
  __syncthreads();

  f32x4 sc[2] = {};
  bf16x8 af[2];
#pragma unroll
  for (int half = 0; half < 2; ++half) {
    int row = lane & 15;
    int chunk = 4 * half + (lane >> 4);
    af[half] = *(const bf16x8*)&Qs[(row * 8 + (chunk ^ (row & 7))) * 8];
  }
#pragma unroll
  for (int p = 0; p < 2; ++p) {
    int col = 16 * (2 * wv + p) + (lane & 15);
#pragma unroll
    for (int half = 0; half < 2; ++half) {
      int chunk = 4 * half + (lane >> 4);
      bf16x8 bfv = *(const bf16x8*)&Ks[(col * 8 + (chunk ^ (col & 7))) * 8];
      sc[p] = __builtin_amdgcn_mfma_f32_16x16x32_bf16(af[half], bfv, sc[p], 0, 0, 0);
    }
  }
  __syncthreads();

#pragma unroll
  for (int p = 0; p < 2; ++p) {
    int col = 16 * (2 * wv + p) + (lane & 15);
    int j = colj[col];
#pragma unroll
    for (int r = 0; r < 4; ++r) {
      int row = (lane >> 4) * 4 + r;
      int i = t0 + row;
      int p0 = pn_l[2 * row], p1 = pn_l[2 * row + 1];
      bool m;
      if (col < 80)      m = (j >= 0) && (j <= i) &&
                             ((i - j) <= 64 || (j & 63) == 0 || j == p0 || j == p1);
      else if (col < 96) m = (j >= 0);
      else               m = (j >= 0) && (j == p0 || j == p1);
      S[row * 132 + col] = m ? ((float)sc[p][r]) * 0.125f : -1e30f;
    }
  }
  __syncthreads();

  {
    int row = tid >> 4, q = tid & 15;
    float v[8];
    float mx = -3e38f;
#pragma unroll
    for (int e = 0; e < 8; ++e) {
      v[e] = S[row * 132 + 8 * q + e];
      mx = fmaxf(mx, v[e]);
    }
#pragma unroll
    for (int off = 1; off < 16; off <<= 1) mx = fmaxf(mx, __shfl_xor(mx, off, 64));
    float sum = 0.f;
#pragma unroll
    for (int e = 0; e < 8; ++e) {
      v[e] = __expf(v[e] - mx);
      sum += v[e];
    }
#pragma unroll
    for (int off = 1; off < 16; off <<= 1) sum += __shfl_xor(sum, off, 64);
    if (q == 0) rinv[row] = 1.0f / sum;
    u32 w0 = (u32)f2bf(v[0]) | ((u32)f2bf(v[1]) << 16);
    u32 w1 = (u32)f2bf(v[2]) | ((u32)f2bf(v[3]) << 16);
    u32 w2 = (u32)f2bf(v[4]) | ((u32)f2bf(v[5]) << 16);
    u32 w3 = (u32)f2bf(v[6]) | ((u32)f2bf(v[7]) << 16);
    uint4 pk = {w0, w1, w2, w3};
    *(uint4*)&P[row * 128 + ((q ^ (row & 7)) << 3)] = pk;
  }

#pragma unroll
  for (int e = 0; e < 8; ++e) {
    int d = d0 + e;
    u32 lo = (u32)h16(vreg[0], e) | ((u32)h16(vreg[1], e) << 16);
    u32 hi = (u32)h16(vreg[2], e) | ((u32)h16(vreg[3], e) << 16);
    int oswz = (cq >> 1) ^ (d & 7) ^ ((d >> 3) & 7);
    uint2 pk2 = {lo, hi};
    *(uint2*)&Vt[d * 128 + oswz * 8 + (cq & 1) * 4] = pk2;
  }
  __syncthreads();

  f32x4 oacc = {};
#pragma unroll
  for (int ks2 = 0; ks2 < 4; ++ks2) {
    int rowp = lane & 15;
    int chp = ks2 * 4 + (lane >> 4);
    bf16x8 pa = *(const bf16x8*)&P[rowp * 128 + ((chp ^ (rowp & 7)) << 3)];
    int dd = wv * 16 + (lane & 15);
    int swz = chp ^ (dd & 7) ^ ((dd >> 3) & 7);
    bf16x8 vb = *(const bf16x8*)&Vt[dd * 128 + swz * 8];
    oacc = __builtin_amdgcn_mfma_f32_16x16x32_bf16(pa, vb, oacc, 0, 0, 0);
  }
  {
    int dd = wv * 16 + (lane & 15);
#pragma unroll
    for (int r = 0; r < 4; ++r) {
      int row = (lane >> 4) * 4 + r;
      y[(size_t)(t0 + row) * NE + h * HD + dd] = f2bf(oacc[r] * rinv[row]);
    }
  }
}

// ---- Persistent mega-kernel: prep | gemm1 | attn | gemm2 with grid barriers ----
__global__ __launch_bounds__(256, 4) void mega(
    const float* __restrict__ x, const float* __restrict__ Wqkv,
    const float* __restrict__ Wout, const int* __restrict__ nidx,
    float* __restrict__ out, u16* __restrict__ xb, u16* __restrict__ WqkvT,
    u16* __restrict__ WoutT, u16* __restrict__ qkvb, u32* __restrict__ bars,
    int D) {
  __shared__ __align__(16) char SM[35584];
  const int tid = threadIdx.x;
  const int bid = blockIdx.x;

  // P0: prep (2048 units, grid-stride)
  for (int u = bid; u < 2048; u += NBLK) {
    __syncthreads();
    prep_unit(u, tid, x, Wqkv, Wout, xb, WqkvT, WoutT, SM);
  }
  grid_barrier(bars + 0);

  // P1: qkv = x @ Wqkv (768 tiles, one per block)
  gemm_phase<1, 64, 6>(xb, WqkvT, qkvb, 3 * NE, NE, SM, bid, tid);
  grid_barrier(bars + 16);

  // P2: attention (1024 units, grid-stride); y overlays xb
  for (int u = bid; u < 1024; u += NBLK) {
    __syncthreads();
    attn_phase(qkvb, nidx, xb, D, SM, u, tid);
  }
  grid_barrier(bars + 32);

  // P3: out = y @ Wout (512 tiles on blocks 0..511)
  if (bid < 512) gemm_phase<0, 32, 4>(xb, WoutT, out, NE, NE, SM, bid, tid);
}

extern "C" void kernel_launch(void* const* d_in, const int* in_sizes, int n_in,
                              void* d_out, int out_size, void* d_ws, size_t ws_size,
                              hipStream_t stream) {
  const float* x    = (const float*)d_in[0];
  const float* Wqkv = (const float*)d_in[1];
  const float* Wout = (const float*)d_in[2];
  const int*   nidx = (const int*)d_in[3];
  float* out = (float*)d_out;

  u16* ws16  = (u16*)d_ws;
  u16* xb    = ws16;                 // 2MB; reused as y after gemm1
  u16* WqkvT = ws16 + 1048576;       // 6MB
  u16* WoutT = ws16 + 4194304;       // 2MB
  u16* qkvb  = ws16 + 5242880;       // 6MB
  u32* bars  = (u32*)((char*)d_ws + (32u << 20));

  const int D = in_sizes[3] / (NH * TT);   // 83

  hipMemsetAsync(bars, 0, 256, stream);    // zero the 3 barrier counters
  mega<<<NBLK, 256, 0, stream>>>(x, Wqkv, Wout, nidx, out,
                                 xb, WqkvT, WoutT, qkvb, bars, D);
}

// Round 14
// 46.087 us; speedup vs baseline: 8.9933x; 8.9933x over previous
//
#include <hip/hip_runtime.h>
#include <math.h>

#define NH 16
#define TT 1024
#define HD 64
#define NE 1024

typedef unsigned int u32;
typedef unsigned short u16;
typedef __bf16 bf16x8 __attribute__((ext_vector_type(8)));
typedef float f32x4 __attribute__((ext_vector_type(4)));

__device__ inline u16 f2bf(float f) {
  u32 u = __builtin_bit_cast(u32, f);
  u32 r = (u + 0x7fffu + ((u >> 16) & 1u)) >> 16;
  return (u16)r;
}
__device__ inline float bf2f(u16 h) {
  return __builtin_bit_cast(float, (u32)h << 16);
}
__device__ inline void gload16(const void* g, void* l) {
  __builtin_amdgcn_global_load_lds((const __attribute__((address_space(1))) void*)g,
                                   (__attribute__((address_space(3))) void*)l, 16, 0, 0);
}
__device__ inline u16 h16(uint4 v, int e) {
  u32 w = ((const u32*)&v)[e >> 1];
  return (e & 1) ? (u16)(w >> 16) : (u16)(w & 0xffffu);
}
__device__ inline void block_bar() {
  asm volatile("" ::: "memory");
  __builtin_amdgcn_s_barrier();
  asm volatile("" ::: "memory");
}

// Fused prep: blocks [0,1024) convert x -> bf16; [1024,2048) transpose weights.
__global__ __launch_bounds__(256) void prep(const float* __restrict__ x,
                                            const float* __restrict__ Wqkv,
                                            const float* __restrict__ Wout,
                                            u16* __restrict__ xb,
                                            u16* __restrict__ WqkvT,
                                            u16* __restrict__ WoutT) {
  __shared__ float tile[64][65];
  const int tid = threadIdx.x;
  const int bx = blockIdx.x;
  if (bx < 1024) {
    int i = bx * 256 + tid;
    float4 f = ((const float4*)x)[i];
    ushort4 o = {f2bf(f.x), f2bf(f.y), f2bf(f.z), f2bf(f.w)};
    ((ushort4*)xb)[i] = o;
    return;
  }
  int b = bx - 1024;
  int nb = b & 63, kb = b >> 6;
  const float* W; u16* WT; int N, n0;
  if (nb < 48) { W = Wqkv; WT = WqkvT; N = 3 * NE; n0 = nb * 64; }
  else         { W = Wout; WT = WoutT; N = NE;     n0 = (nb - 48) * 64; }
  const int k0 = kb * 64;
#pragma unroll
  for (int it = 0; it < 16; ++it) {
    int idx = it * 256 + tid;
    int r = idx >> 6, c = idx & 63;
    tile[r][c] = W[(size_t)(k0 + r) * N + n0 + c];
  }
  __syncthreads();
#pragma unroll
  for (int it = 0; it < 16; ++it) {
    int idx = it * 256 + tid;
    int nn = idx >> 6, kk = idx & 63;
    WT[(size_t)(n0 + nn) * NE + k0 + kk] = f2bf(tile[kk][nn]);
  }
}

// Stage R rows x 64 k of bf16 into LDS, chunk-swizzled: slot(r,kg)=kg^(r&7).
template<int R>
__device__ __forceinline__ void stage_rows(const u16* __restrict__ G, int ldk,
                                           u16* L, int tid) {
#pragma unroll
  for (int it = 0; it < R / 32; ++it) {
    int idx = it * 256 + tid;
    int r = idx >> 3, kg = idx & 7;
    gload16(G + (size_t)r * ldk + ((kg ^ (r & 7)) << 3), L + (idx << 3));
  }
}

// bf16 MFMA GEMM: 64 x NT tile, BK=64, 4 waves split as (col-half x K-HALF):
// wave (wn,kh) computes ALL 64 rows x its NT/2 cols for k-half kh.
// 6 (NT=64) LDS reads per 8 MFMA (was 8/8) -> -25% LDS traffic, 2x MFMA ILP.
// Cross-wave k-half reduce in epilogue via As-as-scratch.
// 2-deep counted-vmcnt prefetch + raw barriers (R9-verified). XCD-aware cols.
// MODE 0: f32 direct write. MODE 1: bf16 qkv scatter [which][h][t][d].
template<int MODE, int NT, int CPX>
__global__ __launch_bounds__(256) void gemm_kh(const u16* __restrict__ A,
                                               const u16* __restrict__ Bt,
                                               void* __restrict__ Cv,
                                               int M, int N, int K) {
  __shared__ u16 As[2][64 * 64];
  __shared__ u16 Bs[2][NT * 64];
  const int tid = threadIdx.x;
  const int lane = tid & 63;
  const int wv = tid >> 6;
  const int wn = wv & 1;         // col half
  const int kh = wv >> 1;        // k half (0: k 0..31, 1: k 32..63)
  const int bid = blockIdx.x;
  const int xcd = bid & 7, loc = bid >> 3;
  const int row0 = (loc / CPX) * 64;
  const int col0 = (xcd * CPX + loc % CPX) * NT;
  const int nsteps = K >> 6;
  constexpr int NI = NT / 64;    // col frags per wave (NT=64 -> 2, NT=32 -> 1)
  static_assert(NT == 64 || NT == 32, "NT");
  constexpr int NIr = (NT == 64) ? 2 : 1;
  constexpr int SPW = 2 + NT / 32;   // staging instr/thread/K-step (4 or 3)

  const u16* Ab = A + (size_t)row0 * K;
  const u16* Bb = Bt + (size_t)col0 * K;

  f32x4 acc[4][NIr] = {};

  stage_rows<64>(Ab, K, As[0], tid);
  stage_rows<NT>(Bb, K, Bs[0], tid);
  stage_rows<64>(Ab + 64, K, As[1], tid);
  stage_rows<NT>(Bb + 64, K, Bs[1], tid);

  for (int ks = 0; ks < nsteps; ++ks) {
    if (ks < nsteps - 1) {
      if constexpr (SPW == 4) asm volatile("s_waitcnt vmcnt(4)" ::: "memory");
      else                    asm volatile("s_waitcnt vmcnt(3)" ::: "memory");
    } else {
      asm volatile("s_waitcnt vmcnt(0)" ::: "memory");
    }
    __builtin_amdgcn_sched_barrier(0);
    block_bar();                      // buf[ks] globally ready

    const int buf = ks & 1;
    const int c = kh * 4 + (lane >> 4);   // k chunk for this wave's k-half
    bf16x8 af[4], bfr[NIr];
#pragma unroll
    for (int mi = 0; mi < 4; ++mi) {
      int r = mi * 16 + (lane & 15);
      af[mi] = *(const bf16x8*)&As[buf][(r * 8 + (c ^ (r & 7))) * 8];
    }
#pragma unroll
    for (int ni = 0; ni < NIr; ++ni) {
      int r = wn * (NT / 2) + ni * 16 + (lane & 15);
      bfr[ni] = *(const bf16x8*)&Bs[buf][(r * 8 + (c ^ (r & 7))) * 8];
    }
#pragma unroll
    for (int mi = 0; mi < 4; ++mi)
#pragma unroll
      for (int ni = 0; ni < NIr; ++ni)
        acc[mi][ni] = __builtin_amdgcn_mfma_f32_16x16x32_bf16(af[mi], bfr[ni], acc[mi][ni], 0, 0, 0);

    block_bar();                      // all waves done reading buf[ks]
    if (ks + 2 < nsteps) {
      stage_rows<64>(Ab + (size_t)(ks + 2) * 64, K, As[buf], tid);
      stage_rows<NT>(Bb + (size_t)(ks + 2) * 64, K, Bs[buf], tid);
    }
  }

  // Cross-wave k-half reduction: kh=1 waves park partials in As (16KB scratch).
  float* scratch = (float*)&As[0][0];
  __syncthreads();
  if (kh == 1) {
#pragma unroll
    for (int mi = 0; mi < 4; ++mi)
#pragma unroll
      for (int ni = 0; ni < NIr; ++ni)
        *(f32x4*)&scratch[(((wn * NIr + ni) * 4 + mi) * 64 + lane) * 4] = acc[mi][ni];
  }
  __syncthreads();
  if (kh == 0) {
    const int cbase = col0 + wn * (NT / 2) + (lane & 15);
#pragma unroll
    for (int mi = 0; mi < 4; ++mi) {
#pragma unroll
      for (int ni = 0; ni < NIr; ++ni) {
        f32x4 o = acc[mi][ni] +
                  *(const f32x4*)&scratch[(((wn * NIr + ni) * 4 + mi) * 64 + lane) * 4];
        int n = cbase + ni * 16;
#pragma unroll
        for (int r = 0; r < 4; ++r) {
          int t = row0 + mi * 16 + (lane >> 4) * 4 + r;
          float val = o[r];
          if (MODE == 0) {
            ((float*)Cv)[(size_t)t * N + n] = val;
          } else {
            int which = n >> 10, h = (n & 1023) >> 6, d = n & 63;
            ((u16*)Cv)[(size_t)which * (NH * TT * HD) + (size_t)h * (TT * HD) +
                       (size_t)t * HD + d] = f2bf(val);
          }
        }
      }
    }
  }
}

// Tiled gathered attention, MFMA QK^T + MFMA PV. (R9 attn5, unchanged.)
__global__ __launch_bounds__(256) void attn5(const u16* __restrict__ qkv,
                                             const int* __restrict__ nidx,
                                             u16* __restrict__ y, int D) {
  __shared__ __align__(16) u16 Qs[16 * 64];
  __shared__ __align__(16) u16 Ks[128 * 64];
  __shared__ __align__(16) u16 Vt[64 * 128];
  __shared__ int pn_l[32];
  __shared__ int colj[128];
  __shared__ float rinv[16];
  float* S = (float*)Ks;
  u16* P = (u16*)((char*)Ks + 8448);

  const int tid = threadIdx.x;
  const int lane = tid & 63;
  const int wv = tid >> 6;
  const int bid = blockIdx.x;
  const int xcd = bid & 7, loc = bid >> 3;
  const int h = xcd * 2 + (loc & 1);
  const int t0 = (loc >> 1) * 16;

  const u16* qh = qkv + (size_t)h * TT * HD;
  const u16* kh = qkv + (size_t)NH * TT * HD + (size_t)h * TT * HD;
  const u16* vh = qkv + 2 * (size_t)NH * TT * HD + (size_t)h * TT * HD;

  if (tid < 32) pn_l[tid] = nidx[((size_t)h * TT + t0 + (tid >> 1)) * D + (tid & 1)];
  if (tid < 128) {
    int row = tid >> 3, slot = tid & 7, ch = slot ^ (row & 7);
    gload16(qh + (size_t)(t0 + row) * HD + ch * 8, Qs + tid * 8);
  }
  __syncthreads();

  if (tid < 128) {
    int c = tid, j;
    if (c < 80) {
      j = t0 - 64 + c;
      if (j < 0) j = -1;
    } else if (c < 96) {
      j = (c - 80) * 64;
      if (j >= t0 - 64) j = -1;
    } else {
      int s = c - 96;
      j = pn_l[s];
      bool keep = (j < t0 - 64) && ((j & 63) != 0);
      if (keep)
        for (int s2 = 0; s2 < s; ++s2)
          if (pn_l[s2] == j) { keep = false; break; }
      if (!keep) j = -1;
    }
    colj[c] = j;
  }
  __syncthreads();

#pragma unroll
  for (int it = 0; it < 4; ++it) {
    int idx = it * 256 + tid;
    int col = idx >> 3, slot = idx & 7, ch = slot ^ (col & 7);
    int j = colj[col]; if (j < 0) j = 0;
    gload16(kh + (size_t)j * HD + ch * 8, Ks + idx * 8);
  }
  const int d0 = (tid & 7) * 8;
  const int cq = tid >> 3;
  uint4 vreg[4];
#pragma unroll
  for (int it = 0; it < 4; ++it) {
    int col = cq * 4 + it;
    int j = colj[col]; if (j < 0) j = 0;
    vreg[it] = *(const uint4*)(vh + (size_t)j * HD + d0);
  }
  __syncthreads();

  f32x4 sc[2] = {};
  bf16x8 af[2];
#pragma unroll
  for (int half = 0; half < 2; ++half) {
    int row = lane & 15;
    int chunk = 4 * half + (lane >> 4);
    af[half] = *(const bf16x8*)&Qs[(row * 8 + (chunk ^ (row & 7))) * 8];
  }
#pragma unroll
  for (int p = 0; p < 2; ++p) {
    int col = 16 * (2 * wv + p) + (lane & 15);
#pragma unroll
    for (int half = 0; half < 2; ++half) {
      int chunk = 4 * half + (lane >> 4);
      bf16x8 bfv = *(const bf16x8*)&Ks[(col * 8 + (chunk ^ (col & 7))) * 8];
      sc[p] = __builtin_amdgcn_mfma_f32_16x16x32_bf16(af[half], bfv, sc[p], 0, 0, 0);
    }
  }
  __syncthreads();

#pragma unroll
  for (int p = 0; p < 2; ++p) {
    int col = 16 * (2 * wv + p) + (lane & 15);
    int j = colj[col];
#pragma unroll
    for (int r = 0; r < 4; ++r) {
      int row = (lane >> 4) * 4 + r;
      int i = t0 + row;
      int p0 = pn_l[2 * row], p1 = pn_l[2 * row + 1];
      bool m;
      if (col < 80)      m = (j >= 0) && (j <= i) &&
                             ((i - j) <= 64 || (j & 63) == 0 || j == p0 || j == p1);
      else if (col < 96) m = (j >= 0);
      else               m = (j >= 0) && (j == p0 || j == p1);
      S[row * 132 + col] = m ? ((float)sc[p][r]) * 0.125f : -1e30f;
    }
  }
  __syncthreads();

  {
    int row = tid >> 4, q = tid & 15;
    float v[8];
    float mx = -3e38f;
#pragma unroll
    for (int e = 0; e < 8; ++e) {
      v[e] = S[row * 132 + 8 * q + e];
      mx = fmaxf(mx, v[e]);
    }
#pragma unroll
    for (int off = 1; off < 16; off <<= 1) mx = fmaxf(mx, __shfl_xor(mx, off, 64));
    float sum = 0.f;
#pragma unroll
    for (int e = 0; e < 8; ++e) {
      v[e] = __expf(v[e] - mx);
      sum += v[e];
    }
#pragma unroll
    for (int off = 1; off < 16; off <<= 1) sum += __shfl_xor(sum, off, 64);
    if (q == 0) rinv[row] = 1.0f / sum;
    u32 w0 = (u32)f2bf(v[0]) | ((u32)f2bf(v[1]) << 16);
    u32 w1 = (u32)f2bf(v[2]) | ((u32)f2bf(v[3]) << 16);
    u32 w2 = (u32)f2bf(v[4]) | ((u32)f2bf(v[5]) << 16);
    u32 w3 = (u32)f2bf(v[6]) | ((u32)f2bf(v[7]) << 16);
    uint4 pk = {w0, w1, w2, w3};
    *(uint4*)&P[row * 128 + ((q ^ (row & 7)) << 3)] = pk;
  }

#pragma unroll
  for (int e = 0; e < 8; ++e) {
    int d = d0 + e;
    u32 lo = (u32)h16(vreg[0], e) | ((u32)h16(vreg[1], e) << 16);
    u32 hi = (u32)h16(vreg[2], e) | ((u32)h16(vreg[3], e) << 16);
    int oswz = (cq >> 1) ^ (d & 7) ^ ((d >> 3) & 7);
    uint2 pk2 = {lo, hi};
    *(uint2*)&Vt[d * 128 + oswz * 8 + (cq & 1) * 4] = pk2;
  }
  __syncthreads();

  f32x4 oacc = {};
#pragma unroll
  for (int ks2 = 0; ks2 < 4; ++ks2) {
    int rowp = lane & 15;
    int chp = ks2 * 4 + (lane >> 4);
    bf16x8 pa = *(const bf16x8*)&P[rowp * 128 + ((chp ^ (rowp & 7)) << 3)];
    int dd = wv * 16 + (lane & 15);
    int swz = chp ^ (dd & 7) ^ ((dd >> 3) & 7);
    bf16x8 vb = *(const bf16x8*)&Vt[dd * 128 + swz * 8];
    oacc = __builtin_amdgcn_mfma_f32_16x16x32_bf16(pa, vb, oacc, 0, 0, 0);
  }
  {
    int dd = wv * 16 + (lane & 15);
#pragma unroll
    for (int r = 0; r < 4; ++r) {
      int row = (lane >> 4) * 4 + r;
      y[(size_t)(t0 + row) * NE + h * HD + dd] = f2bf(oacc[r] * rinv[row]);
    }
  }
}

extern "C" void kernel_launch(void* const* d_in, const int* in_sizes, int n_in,
                              void* d_out, int out_size, void* d_ws, size_t ws_size,
                              hipStream_t stream) {
  const float* x    = (const float*)d_in[0];
  const float* Wqkv = (const float*)d_in[1];
  const float* Wout = (const float*)d_in[2];
  const int*   nidx = (const int*)d_in[3];
  float* out = (float*)d_out;

  u16* ws16  = (u16*)d_ws;
  u16* xb    = ws16;                 // 2MB; reused as y after gemm1
  u16* WqkvT = ws16 + 1048576;       // 6MB
  u16* WoutT = ws16 + 4194304;       // 2MB
  u16* qkvb  = ws16 + 5242880;       // 6MB

  const int D = in_sizes[3] / (NH * TT);   // 83

  prep<<<2048, 256, 0, stream>>>(x, Wqkv, Wout, xb, WqkvT, WoutT);

  // qkv = x @ Wqkv. 768 blocks, 3/CU, k-half wave split.
  gemm_kh<1, 64, 6><<<768, 256, 0, stream>>>(xb, WqkvT, qkvb, TT, 3 * NE, NE);

  // tiled gathered attention; y (bf16) overlays xb. XCD-local heads.
  attn5<<<1024, 256, 0, stream>>>(qkvb, nidx, xb, D);

  // out = y @ Wout. 512 blocks, 2/CU, k-half wave split.
  gemm_kh<0, 32, 4><<<512, 256, 0, stream>>>(xb, WoutT, out, TT, NE, NE);
}